// Round 6
// baseline (244.242 us; speedup 1.0000x reference)
//
#include <hip/hip_runtime.h>
#include <hip/hip_bf16.h>

typedef unsigned int u32;
typedef unsigned short u16;
typedef __attribute__((ext_vector_type(8))) __bf16 bf16x8;
typedef __attribute__((ext_vector_type(4))) float f32x4;

#define N_CAP 10
#define D_CAP 16
#define NN 160
#define KK 2048

__device__ __forceinline__ u32 pack_hi(float f0, float f1) {
  u32 u0 = __builtin_bit_cast(u32, f0), u1 = __builtin_bit_cast(u32, f1);
  return (u0 >> 16) | (u1 & 0xFFFF0000u);
}
__device__ __forceinline__ float hi_part(float f) {
  u32 u = __builtin_bit_cast(u32, f) & 0xFFFF0000u;
  return __builtin_bit_cast(float, u);
}
union U4B8 { uint4 u; bf16x8 b; };

// ============================ W pre-split =================================
// W[k][n] f32 -> Whi/Wlo bf16 in MFMA-B-fragment order: [(k>>3)][n][k&7]
__global__ void split_w(const float* __restrict__ W, u16* __restrict__ Whi,
                        u16* __restrict__ Wlo) {
  const int tid = blockIdx.x * 256 + threadIdx.x;   // 327680 exact
  const int k = tid / NN, n = tid - k * NN;
  const float f = W[tid];
  const u32 u = __builtin_bit_cast(u32, f);
  const float lo = f - hi_part(f);
  const int dst = ((k >> 3) * NN + n) * 8 + (k & 7);
  Whi[dst] = (u16)(u >> 16);
  Wlo[dst] = (u16)(__builtin_bit_cast(u32, lo) >> 16);
}

// ============================ main kernel =================================
#define BM2 32
#define BK2 64
#define NST2 (KK / BK2)     // 32
#define THR2 320            // 5 waves
#define LDST2 72            // u16 per As row (64 data + 8 pad) = 144 B
#define ATILE2 2304         // 32*72 u16 per (hi or lo) tile
#define BUFU16 4608         // hi+lo per buffer
#define SMEM2 20992         // hat 32*164*4; staging (2 buf = 18432 B) fits under

__global__ __launch_bounds__(THR2, 3) void capsule_main(
    const float* __restrict__ X, const u16* __restrict__ Whi,
    const u16* __restrict__ Wlo, float* __restrict__ out) {
  __shared__ __align__(16) char smem[SMEM2];
  u16* As = (u16*)smem;
  float* hat = (float*)smem;   // reused after GEMM: [32][164] f32

  const int t = threadIdx.x;
  const int rbase = blockIdx.x * BM2;
  const int lane = t & 63;
  const int w = t >> 6;               // col group 0..4 (cols 32w..+32)
  const int l15 = lane & 15;
  const int q = lane >> 4;            // 0..3

  // A loader: t<256: row ar, k-offset ak within step
  const int ar = t >> 3;              // 0..31
  const int ak = (t & 7) * 8;         // 0..56
  const float* gA = X + (size_t)(rbase + ar) * KK + ak;
  const int wA = ar * LDST2 + ak;     // u16 index in tile

  // B fragment base (u16 elems): ((s*8 + h*4 + q)*NN + 32w + 16i + l15)*8
  const int gB0 = (q * NN + 32 * w + l15) * 8;
  // offsets: s*10240, h*5120, i*128

  f32x4 acc00 = {0,0,0,0}, acc01 = {0,0,0,0}, acc10 = {0,0,0,0}, acc11 = {0,0,0,0};

  float4 paA0, paA1, paB0, paB1;
  bf16x8 BAh[2][2], BAl[2][2], BBh[2][2], BBl[2][2];

  // ---- prologue: A regs for steps 0,1; B regs for step 0; stage step 0 ----
  if (t < 256) {
    paA0 = *(const float4*)(gA);            paA1 = *(const float4*)(gA + 4);
    paB0 = *(const float4*)(gA + BK2);      paB1 = *(const float4*)(gA + BK2 + 4);
  }
#pragma unroll
  for (int h = 0; h < 2; ++h)
#pragma unroll
    for (int i = 0; i < 2; ++i) {
      BAh[h][i] = *(const bf16x8*)(Whi + gB0 + h * 5120 + i * 128);
      BAl[h][i] = *(const bf16x8*)(Wlo + gB0 + h * 5120 + i * 128);
    }
  if (t < 256) {
    uint4 hi, lo;
    hi.x = pack_hi(paA0.x, paA0.y); hi.y = pack_hi(paA0.z, paA0.w);
    hi.z = pack_hi(paA1.x, paA1.y); hi.w = pack_hi(paA1.z, paA1.w);
    lo.x = pack_hi(paA0.x - hi_part(paA0.x), paA0.y - hi_part(paA0.y));
    lo.y = pack_hi(paA0.z - hi_part(paA0.z), paA0.w - hi_part(paA0.w));
    lo.z = pack_hi(paA1.x - hi_part(paA1.x), paA1.y - hi_part(paA1.y));
    lo.w = pack_hi(paA1.z - hi_part(paA1.z), paA1.w - hi_part(paA1.w));
    *(uint4*)(As + wA) = hi;
    *(uint4*)(As + ATILE2 + wA) = lo;
  }
  __syncthreads();

  // STEP2(S, LA*, SA*, BH,BL current, BHN,BLN next):
  //   load A(step S+2) into LA; stage SA (step S+1) to buf[(S+1)&1];
  //   load B(step S+1) into BHN/BLN; MFMA step S from buf[S&1] with BH/BL.
#define STEP2(S, LA0, LA1, SA0, SA1, BH, BL, BHN, BLN)                          \
  {                                                                             \
    if ((S) + 1 < NST2) {                                                       \
      const int bo = gB0 + ((S) + 1) * 10240;                                   \
      _Pragma("unroll") for (int h = 0; h < 2; ++h)                             \
      _Pragma("unroll") for (int i = 0; i < 2; ++i) {                           \
        BHN[h][i] = *(const bf16x8*)(Whi + bo + h * 5120 + i * 128);            \
        BLN[h][i] = *(const bf16x8*)(Wlo + bo + h * 5120 + i * 128);            \
      }                                                                         \
    }                                                                           \
    if (t < 256 && (S) + 2 < NST2) {                                            \
      LA0 = *(const float4*)(gA + ((S) + 2) * BK2);                             \
      LA1 = *(const float4*)(gA + ((S) + 2) * BK2 + 4);                         \
    }                                                                           \
    const u16* ab = As + ((S) & 1) * BUFU16;                                    \
    _Pragma("unroll") for (int h = 0; h < 2; ++h) {                             \
      bf16x8 ah0 = *(const bf16x8*)(ab + l15 * LDST2 + h * 32 + q * 8);         \
      bf16x8 ah1 = *(const bf16x8*)(ab + (16 + l15) * LDST2 + h * 32 + q * 8);  \
      bf16x8 al0 = *(const bf16x8*)(ab + ATILE2 + l15 * LDST2 + h * 32 + q * 8);\
      bf16x8 al1 = *(const bf16x8*)(ab + ATILE2 + (16 + l15) * LDST2 + h * 32 + q * 8); \
      acc00 = __builtin_amdgcn_mfma_f32_16x16x32_bf16(ah0, BH[h][0], acc00, 0, 0, 0); \
      acc00 = __builtin_amdgcn_mfma_f32_16x16x32_bf16(ah0, BL[h][0], acc00, 0, 0, 0); \
      acc00 = __builtin_amdgcn_mfma_f32_16x16x32_bf16(al0, BH[h][0], acc00, 0, 0, 0); \
      acc01 = __builtin_amdgcn_mfma_f32_16x16x32_bf16(ah0, BH[h][1], acc01, 0, 0, 0); \
      acc01 = __builtin_amdgcn_mfma_f32_16x16x32_bf16(ah0, BL[h][1], acc01, 0, 0, 0); \
      acc01 = __builtin_amdgcn_mfma_f32_16x16x32_bf16(al0, BH[h][1], acc01, 0, 0, 0); \
      acc10 = __builtin_amdgcn_mfma_f32_16x16x32_bf16(ah1, BH[h][0], acc10, 0, 0, 0); \
      acc10 = __builtin_amdgcn_mfma_f32_16x16x32_bf16(ah1, BL[h][0], acc10, 0, 0, 0); \
      acc10 = __builtin_amdgcn_mfma_f32_16x16x32_bf16(al1, BH[h][0], acc10, 0, 0, 0); \
      acc11 = __builtin_amdgcn_mfma_f32_16x16x32_bf16(ah1, BH[h][1], acc11, 0, 0, 0); \
      acc11 = __builtin_amdgcn_mfma_f32_16x16x32_bf16(ah1, BL[h][1], acc11, 0, 0, 0); \
      acc11 = __builtin_amdgcn_mfma_f32_16x16x32_bf16(al1, BH[h][1], acc11, 0, 0, 0); \
    }                                                                           \
    if (t < 256 && (S) + 1 < NST2) {                                            \
      u16* wb = As + (((S) + 1) & 1) * BUFU16;                                  \
      uint4 hi, lo;                                                             \
      hi.x = pack_hi(SA0.x, SA0.y); hi.y = pack_hi(SA0.z, SA0.w);               \
      hi.z = pack_hi(SA1.x, SA1.y); hi.w = pack_hi(SA1.z, SA1.w);               \
      lo.x = pack_hi(SA0.x - hi_part(SA0.x), SA0.y - hi_part(SA0.y));           \
      lo.y = pack_hi(SA0.z - hi_part(SA0.z), SA0.w - hi_part(SA0.w));           \
      lo.z = pack_hi(SA1.x - hi_part(SA1.x), SA1.y - hi_part(SA1.y));           \
      lo.w = pack_hi(SA1.z - hi_part(SA1.z), SA1.w - hi_part(SA1.w));           \
      *(uint4*)(wb + wA) = hi;                                                  \
      *(uint4*)(wb + ATILE2 + wA) = lo;                                         \
    }                                                                           \
    __syncthreads();                                                            \
  }

  for (int s = 0; s < NST2; s += 2) {
    STEP2(s,     paA0, paA1, paB0, paB1, BAh, BAl, BBh, BBl)
    STEP2(s + 1, paB0, paB1, paA0, paA1, BBh, BBl, BAh, BAl)
  }
#undef STEP2

  // last STEP2's barrier sealed all LDS reads; safe to overwrite with hat
#pragma unroll
  for (int r = 0; r < 4; ++r) {
    // C/D layout (m89/m91): col(n) = lane&15, row(m) = (lane>>4)*4 + reg
    const int rowb = 4 * q + r;
    const int colb = 32 * w + l15;
    hat[rowb * 164 + colb]             = acc00[r];
    hat[rowb * 164 + colb + 16]        = acc01[r];
    hat[(rowb + 16) * 164 + colb]      = acc10[r];
    hat[(rowb + 16) * 164 + colb + 16] = acc11[r];
  }
  __syncthreads();

  // ---- routing: 1 thread per row (proven in R4/R5) ----
  if (t < BM2) {
    const int r = t;
    float bb[N_CAP];
#pragma unroll
    for (int n = 0; n < N_CAP; ++n) bb[n] = 0.f;
    float v[D_CAP];
#pragma unroll
    for (int it = 0; it < 3; ++it) {
      float mx = bb[0];
#pragma unroll
      for (int n = 1; n < N_CAP; ++n) mx = fmaxf(mx, bb[n]);
      float c[N_CAP], se = 0.f;
#pragma unroll
      for (int n = 0; n < N_CAP; ++n) { c[n] = __expf(bb[n] - mx); se += c[n]; }
      const float inv = 1.f / se;
      float sd[D_CAP], s2 = 0.f;
#pragma unroll
      for (int d = 0; d < D_CAP; ++d) {
        float x = 0.f;
#pragma unroll
        for (int n = 0; n < N_CAP; ++n) x += c[n] * hat[r * 164 + n * D_CAP + d];
        x *= inv;
        sd[d] = x;
        s2 += x * x;
      }
      const float scale = s2 / ((1.f + s2) * sqrtf(s2 + 1e-7f));
#pragma unroll
      for (int d = 0; d < D_CAP; ++d) v[d] = scale * sd[d];
      if (it < 2) {
#pragma unroll
        for (int n = 0; n < N_CAP; ++n) {
          float dd = 0.f;
#pragma unroll
          for (int d = 0; d < D_CAP; ++d) dd += hat[r * 164 + n * D_CAP + d] * v[d];
          bb[n] += dd;
        }
      }
    }
#pragma unroll
    for (int d = 0; d < D_CAP; ++d)
      out[(size_t)(rbase + r) * D_CAP + d] = v[d];
  }
}

// ==================== R5 fallback (proven) if ws too small =================
#define BM 64
#define BK 32
#define NSTEPS (KK / BK)
#define THREADS 640
#define LDST 40
#define AS_TILE (BM * LDST)
#define HAT_STRIDE 164
#define SMEM_BYTES (BM * HAT_STRIDE * 4)

__global__ __launch_bounds__(THREADS, 3) void capsule_fb(
    const float* __restrict__ X, const float* __restrict__ W, float* __restrict__ out) {
  __shared__ __align__(16) char smem[SMEM_BYTES];
  u16* As_hi = (u16*)smem;
  u16* As_lo = As_hi + AS_TILE;
  float* hat = (float*)smem;
  const int t = threadIdx.x;
  const int rbase = blockIdx.x * BM;
  const int lane = t & 63;
  const int w = t >> 6;
  const int wip = (w >= 5) ? 1 : 0;
  const int wjp = w - 5 * wip;
  const int l15 = lane & 15;
  const int q = lane >> 4;
  const int ar = t >> 2;
  const int ak = (t & 3) * 8;
  const float* gA = X + (size_t)(rbase + ar) * KK + ak;
  const float* gB = W + (q * 8) * NN + 32 * wjp + l15;
  f32x4 acc00 = {0,0,0,0}, acc01 = {0,0,0,0}, acc10 = {0,0,0,0}, acc11 = {0,0,0,0};
  float4 pa0A, pa1A, pa0B, pa1B;
  if (t < 256) {
    pa0A = *(const float4*)(gA);        pa1A = *(const float4*)(gA + 4);
    pa0B = *(const float4*)(gA + BK);   pa1B = *(const float4*)(gA + BK + 4);
  }
  float buA[16], buB[16];
#pragma unroll
  for (int j = 0; j < 8; ++j) { buA[j] = gB[j * NN]; buA[8 + j] = gB[16 + j * NN]; }
#define STEP(S, PA0, PA1, BU, BNXT)                                              \
  {                                                                              \
    __syncthreads();                                                             \
    if (t < 256) {                                                               \
      uint4 hi, lo;                                                              \
      hi.x = pack_hi(PA0.x, PA0.y); hi.y = pack_hi(PA0.z, PA0.w);                \
      hi.z = pack_hi(PA1.x, PA1.y); hi.w = pack_hi(PA1.z, PA1.w);                \
      lo.x = pack_hi(PA0.x - hi_part(PA0.x), PA0.y - hi_part(PA0.y));            \
      lo.y = pack_hi(PA0.z - hi_part(PA0.z), PA0.w - hi_part(PA0.w));            \
      lo.z = pack_hi(PA1.x - hi_part(PA1.x), PA1.y - hi_part(PA1.y));            \
      lo.w = pack_hi(PA1.z - hi_part(PA1.z), PA1.w - hi_part(PA1.w));            \
      *(uint4*)(As_hi + ar * LDST + ak) = hi;                                    \
      *(uint4*)(As_lo + ar * LDST + ak) = lo;                                    \
    }                                                                            \
    __syncthreads();                                                             \
    if (t < 256 && (S) + 2 < NSTEPS) {                                           \
      PA0 = *(const float4*)(gA + ((S) + 2) * BK);                               \
      PA1 = *(const float4*)(gA + ((S) + 2) * BK + 4);                           \
    }                                                                            \
    if ((S) + 1 < NSTEPS) {                                                      \
      const float* b = gB + ((S) + 1) * (BK * NN);                               \
      _Pragma("unroll")                                                          \
      for (int j = 0; j < 8; ++j) { BNXT[j] = b[j * NN]; BNXT[8 + j] = b[16 + j * NN]; } \
    }                                                                            \
    U4B8 bh0, bl0, bh1, bl1;                                                     \
    bh0.u.x = pack_hi(BU[0], BU[1]);  bh0.u.y = pack_hi(BU[2], BU[3]);           \
    bh0.u.z = pack_hi(BU[4], BU[5]);  bh0.u.w = pack_hi(BU[6], BU[7]);           \
    bh1.u.x = pack_hi(BU[8], BU[9]);  bh1.u.y = pack_hi(BU[10], BU[11]);         \
    bh1.u.z = pack_hi(BU[12], BU[13]); bh1.u.w = pack_hi(BU[14], BU[15]);        \
    float lb[16];                                                                \
    _Pragma("unroll")                                                            \
    for (int j = 0; j < 16; ++j) lb[j] = BU[j] - hi_part(BU[j]);                 \
    bl0.u.x = pack_hi(lb[0], lb[1]);  bl0.u.y = pack_hi(lb[2], lb[3]);           \
    bl0.u.z = pack_hi(lb[4], lb[5]);  bl0.u.w = pack_hi(lb[6], lb[7]);           \
    bl1.u.x = pack_hi(lb[8], lb[9]);  bl1.u.y = pack_hi(lb[10], lb[11]);         \
    bl1.u.z = pack_hi(lb[12], lb[13]); bl1.u.w = pack_hi(lb[14], lb[15]);        \
    bf16x8 ah0 = *(const bf16x8*)(As_hi + (32 * wip + l15) * LDST + q * 8);      \
    bf16x8 ah1 = *(const bf16x8*)(As_hi + (32 * wip + 16 + l15) * LDST + q * 8); \
    bf16x8 al0 = *(const bf16x8*)(As_lo + (32 * wip + l15) * LDST + q * 8);      \
    bf16x8 al1 = *(const bf16x8*)(As_lo + (32 * wip + 16 + l15) * LDST + q * 8); \
    acc00 = __builtin_amdgcn_mfma_f32_16x16x32_bf16(ah0, bh0.b, acc00, 0, 0, 0); \
    acc00 = __builtin_amdgcn_mfma_f32_16x16x32_bf16(ah0, bl0.b, acc00, 0, 0, 0); \
    acc00 = __builtin_amdgcn_mfma_f32_16x16x32_bf16(al0, bh0.b, acc00, 0, 0, 0); \
    acc01 = __builtin_amdgcn_mfma_f32_16x16x32_bf16(ah0, bh1.b, acc01, 0, 0, 0); \
    acc01 = __builtin_amdgcn_mfma_f32_16x16x32_bf16(ah0, bl1.b, acc01, 0, 0, 0); \
    acc01 = __builtin_amdgcn_mfma_f32_16x16x32_bf16(al0, bh1.b, acc01, 0, 0, 0); \
    acc10 = __builtin_amdgcn_mfma_f32_16x16x32_bf16(ah1, bh0.b, acc10, 0, 0, 0); \
    acc10 = __builtin_amdgcn_mfma_f32_16x16x32_bf16(ah1, bl0.b, acc10, 0, 0, 0); \
    acc10 = __builtin_amdgcn_mfma_f32_16x16x32_bf16(al1, bh0.b, acc10, 0, 0, 0); \
    acc11 = __builtin_amdgcn_mfma_f32_16x16x32_bf16(ah1, bh1.b, acc11, 0, 0, 0); \
    acc11 = __builtin_amdgcn_mfma_f32_16x16x32_bf16(ah1, bl1.b, acc11, 0, 0, 0); \
    acc11 = __builtin_amdgcn_mfma_f32_16x16x32_bf16(al1, bh1.b, acc11, 0, 0, 0); \
  }
  for (int s = 0; s < NSTEPS; s += 2) {
    STEP(s,     pa0A, pa1A, buA, buB)
    STEP(s + 1, pa0B, pa1B, buB, buA)
  }
#undef STEP
  __syncthreads();
#pragma unroll
  for (int r = 0; r < 4; ++r) {
    const int rowb = 32 * wip + 4 * q + r;
    const int colb = 32 * wjp + l15;
    hat[rowb * HAT_STRIDE + colb]             = acc00[r];
    hat[rowb * HAT_STRIDE + colb + 16]        = acc01[r];
    hat[(rowb + 16) * HAT_STRIDE + colb]      = acc10[r];
    hat[(rowb + 16) * HAT_STRIDE + colb + 16] = acc11[r];
  }
  __syncthreads();
  if (t < BM) {
    const int r = t;
    float bb[N_CAP];
#pragma unroll
    for (int n = 0; n < N_CAP; ++n) bb[n] = 0.f;
    float v[D_CAP];
#pragma unroll
    for (int it = 0; it < 3; ++it) {
      float mx = bb[0];
#pragma unroll
      for (int n = 1; n < N_CAP; ++n) mx = fmaxf(mx, bb[n]);
      float c[N_CAP], se = 0.f;
#pragma unroll
      for (int n = 0; n < N_CAP; ++n) { c[n] = __expf(bb[n] - mx); se += c[n]; }
      const float inv = 1.f / se;
      float sd[D_CAP], s2 = 0.f;
#pragma unroll
      for (int d = 0; d < D_CAP; ++d) {
        float x = 0.f;
#pragma unroll
        for (int n = 0; n < N_CAP; ++n) x += c[n] * hat[r * HAT_STRIDE + n * D_CAP + d];
        x *= inv;
        sd[d] = x;
        s2 += x * x;
      }
      const float scale = s2 / ((1.f + s2) * sqrtf(s2 + 1e-7f));
#pragma unroll
      for (int d = 0; d < D_CAP; ++d) v[d] = scale * sd[d];
      if (it < 2) {
#pragma unroll
        for (int n = 0; n < N_CAP; ++n) {
          float dd = 0.f;
#pragma unroll
          for (int d = 0; d < D_CAP; ++d) dd += hat[r * HAT_STRIDE + n * D_CAP + d] * v[d];
          bb[n] += dd;
        }
      }
    }
#pragma unroll
    for (int d = 0; d < D_CAP; ++d)
      out[(size_t)(rbase + r) * D_CAP + d] = v[d];
  }
}

extern "C" void kernel_launch(void* const* d_in, const int* in_sizes, int n_in,
                              void* d_out, int out_size, void* d_ws, size_t ws_size,
                              hipStream_t stream) {
  const float* X = (const float*)d_in[0];   // inputs [16384][2048] f32
  const float* W = (const float*)d_in[1];   // kernel [2048][160] f32
  if (n_in >= 2 && in_sizes[0] == KK * NN) {
    X = (const float*)d_in[1];
    W = (const float*)d_in[0];
  }
  const size_t need = (size_t)2 * KK * NN * sizeof(u16);  // 1.25 MB
  if (ws_size >= need) {
    u16* Whi = (u16*)d_ws;
    u16* Wlo = Whi + (size_t)KK * NN;
    split_w<<<(KK * NN) / 256, 256, 0, stream>>>(W, Whi, Wlo);
    capsule_main<<<16384 / BM2, THR2, 0, stream>>>(X, Whi, Wlo, (float*)d_out);
  } else {
    capsule_fb<<<16384 / BM, THREADS, 0, stream>>>(X, W, (float*)d_out);
  }
}